// Round 14
// baseline (187.112 us; speedup 1.0000x reference)
//
#include <hip/hip_runtime.h>

typedef __bf16 bf16x8 __attribute__((ext_vector_type(8)));
typedef float f32x4 __attribute__((ext_vector_type(4)));

#define DI __device__ __forceinline__

// Pinned counted waitcnt: memory clobber + sched_barrier so global_load_lds
// intrinsics cannot be reordered around it (rule #18).
#define WAIT_VMCNT(N)                                        \
  do {                                                       \
    __builtin_amdgcn_sched_barrier(0);                       \
    asm volatile("s_waitcnt vmcnt(" #N ")" ::: "memory");    \
    __builtin_amdgcn_sched_barrier(0);                       \
  } while (0)

DI unsigned short f2bf(float f) {
  unsigned int u = __float_as_uint(f);
  u += 0x7FFFu + ((u >> 16) & 1u);
  return (unsigned short)(u >> 16);
}

DI unsigned cvt_pk_bf16(float a, float b) {  // lo=bf16(a), hi=bf16(b)
  unsigned r;
  asm("v_cvt_pk_bf16_f32 %0, %1, %2" : "=v"(r) : "v"(a), "v"(b));
  return r;
}

DI float exp2_fast(float x) {  // raw v_exp_f32 (2^x); exp2(-inf)=0
  float r;
  asm("v_exp_f32 %0, %1" : "=v"(r) : "v"(x));
  return r;
}

DI void fence() { asm volatile("" ::: "memory"); }
DI void bar() { fence(); __builtin_amdgcn_s_barrier(); fence(); }

DI bf16x8 ld16(const void* p) {
  union { uint4 u; bf16x8 b; } c;
  c.u = *reinterpret_cast<const uint4*>(p);
  return c.b;
}

DI f32x4 mfma16(bf16x8 a, bf16x8 b, f32x4 c) {
  return __builtin_amdgcn_mfma_f32_16x16x32_bf16(a, b, c, 0, 0, 0);
}

DI void gload_lds16(const void* g, void* l) {
  __builtin_amdgcn_global_load_lds(
      (const __attribute__((address_space(1))) unsigned int*)g,
      (__attribute__((address_space(3))) unsigned int*)l, 16, 0, 0);
}

// ---------------- fused fp32 -> bf16 convert (x, w_qkv, w_proj) ----------------
__global__ void cvt_all(const float* __restrict__ x, const float* __restrict__ wq,
                        const float* __restrict__ wp,
                        unsigned short* __restrict__ xb, unsigned short* __restrict__ wqb,
                        unsigned short* __restrict__ wpb) {
  int i = blockIdx.x * blockDim.x + threadIdx.x;  // float4 index
  const float* s;
  unsigned short* d;
  int off;
  if (i < 2097152) { s = x; d = xb; off = i; }
  else if (i < 2097152 + 786432) { s = wq; d = wqb; off = i - 2097152; }
  else { s = wp; d = wpb; off = i - (2097152 + 786432); }
  float4 v = reinterpret_cast<const float4*>(s)[off];
  uint2 o;
  o.x = cvt_pk_bf16(v.x, v.y);
  o.y = cvt_pk_bf16(v.z, v.w);
  reinterpret_cast<uint2*>(d)[off] = o;
}

// ---------------- GEMM: C[M,N] = A[M,K] * W[N,K]^T + bias ----------------
// PROVEN round-1 structure: 128x128 tile, BK=64, 4 waves (2x2), single-buffered
// LDS (A 16K | B 16K), full drain + barrier per K-step. XOR bank-swizzle on the
// pre-swizzled global source + again on ds_read (involution).
// MODE 0: out = fp32 row-major [M][N] (+bias)
// MODE 1: qkv scatter -> Q (scaled log2e/8), K head-major; V transposed [bh][d][t]
//         (V^T stores packed as uint2: in-lane r's are 4 consecutive t)
template <int N, int MODE>
__global__ __launch_bounds__(256)
void gemm_bt(const unsigned short* __restrict__ A,
             const unsigned short* __restrict__ W,
             const float* __restrict__ bias,
             float* __restrict__ out,
             unsigned short* __restrict__ qo,
             unsigned short* __restrict__ ko,
             unsigned short* __restrict__ vo) {
  constexpr int K = 1024;
  __shared__ __align__(16) char smem[32768];  // A tile 16K | B tile 16K
  char* Asm = smem;
  char* Bsm = smem + 16384;
  const int tid = threadIdx.x;
  const int ln = tid & 63;
  const int w  = tid >> 6;
  const int wm = w >> 1, wn = w & 1;
  const int g = ln >> 4, q = ln & 15;
  const int m0 = blockIdx.x * 128;
  const int n0 = blockIdx.y * 128;

  f32x4 acc[4][4] = {};

  for (int kt = 0; kt < K / 64; ++kt) {
    if (kt) bar();  // previous compute's LDS reads done before overwrite
#pragma unroll
    for (int i = 0; i < 4; ++i) {
      const int chunk = i * 4 + w;                 // [0,16): full 16 KB tile
      const int o = chunk * 1024 + ln * 16;
      const int row = o >> 7;
      const int colb = (o & 127) ^ ((row & 7) << 4);
      gload_lds16((const char*)A + ((size_t)(m0 + row) * K + kt * 64) * 2 + colb,
                  Asm + chunk * 1024);
      gload_lds16((const char*)W + ((size_t)(n0 + row) * K + kt * 64) * 2 + colb,
                  Bsm + chunk * 1024);
    }
    WAIT_VMCNT(0);
    bar();
#pragma unroll
    for (int ks = 0; ks < 2; ++ks) {
      bf16x8 av[4], bv[4];
#pragma unroll
      for (int mf = 0; mf < 4; ++mf) {
        const int row = wm * 64 + mf * 16 + q;
        av[mf] = ld16(Asm + ((row * 128 + ks * 64 + g * 16) ^ ((row & 7) << 4)));
      }
#pragma unroll
      for (int nf = 0; nf < 4; ++nf) {
        const int row = wn * 64 + nf * 16 + q;
        bv[nf] = ld16(Bsm + ((row * 128 + ks * 64 + g * 16) ^ ((row & 7) << 4)));
      }
#pragma unroll
      for (int mf = 0; mf < 4; ++mf)
#pragma unroll
        for (int nf = 0; nf < 4; ++nf)
          acc[mf][nf] = mfma16(av[mf], bv[nf], acc[mf][nf]);
    }
  }

#pragma unroll
  for (int nf = 0; nf < 4; ++nf) {
    const int col = n0 + wn * 64 + nf * 16 + q;
    const float bv = bias[col];
#pragma unroll
    for (int mf = 0; mf < 4; ++mf) {
      const int rbase = m0 + wm * 64 + mf * 16 + g * 4;
      if constexpr (MODE == 0) {
#pragma unroll
        for (int r = 0; r < 4; ++r)
          out[(size_t)(rbase + r) * N + col] = acc[mf][nf][r] + bv;
      } else {
        const int b = rbase >> 11, t0 = rbase & 2047;  // 4 consecutive t, same b
        if (col < 1024) {
          const int h = col >> 6, d = col & 63;
          unsigned short* qp = qo + ((((size_t)b * 16 + h) << 11) + t0) * 64 + d;
#pragma unroll
          for (int r = 0; r < 4; ++r)
            qp[r * 64] = f2bf((acc[mf][nf][r] + bv) * 0.18033688011112042f);
        } else if (col < 2048) {
          const int c = col - 1024;
          const int h = c >> 6, d = c & 63;
          unsigned short* kp = ko + ((((size_t)b * 16 + h) << 11) + t0) * 64 + d;
#pragma unroll
          for (int r = 0; r < 4; ++r)
            kp[r * 64] = f2bf(acc[mf][nf][r] + bv);
        } else {
          const int c = col - 2048;
          const int h = c >> 6, d = c & 63;
          uint2 pk;
          pk.x = cvt_pk_bf16(acc[mf][nf][0] + bv, acc[mf][nf][1] + bv);
          pk.y = cvt_pk_bf16(acc[mf][nf][2] + bv, acc[mf][nf][3] + bv);
          *(uint2*)(vo + ((((size_t)b * 16 + h) << 6) + d) * 2048 + t0) = pk;
        }
      }
    }
  }
}

// attention swizzle: slot bits 0-1 from row bits 0-1, slot bit 2 from row BIT 3.
// Conflict-free for both the permuted K-read and the V-read (r12, measured 0).
DI int asb(int row) { return ((row & 3) | (((row >> 3) & 1) << 2)) << 4; }

// ---------------- flash attention (causal), MERGED-PAIR + SHARED FRAGMENTS ----------------
// r13 merged-pair structure (one kv-loop of 32-p staged tiles; hi consumes all,
// lo consumes j<=p; K/V dbuf + counted vmcnt(4); permuted-A-row QK^T; in-register
// PV B-operand; asb swizzle). NEW: on dual iterations the hi and lo tile_steps
// read IDENTICAL K/V LDS fragments (rows don't depend on the q-tile), so the 8
// K-frag and 8 V-frag ds_read_b128 are hoisted and SHARED -> DS traffic on dual
// iters halves (32 -> 16 b128), -26% block-average on the ~75%-loaded DS pipe.
__global__ __launch_bounds__(256, 4)
void attn_fwd(const unsigned short* __restrict__ Qb,
              const unsigned short* __restrict__ Kb,
              const unsigned short* __restrict__ Vtb,
              unsigned short* __restrict__ Yb) {
  __shared__ __align__(16) char smem[32768];
  // buf0: K [0,8K) V [8K,16K); buf1: K [16K,24K) V [24K,32K)
  const int tid = threadIdx.x;
  const int ln = tid & 63;
  const int w = tid >> 6;
  const int g = ln >> 4, q = ln & 15;
  const int bh = blockIdx.x;
  const int pair = blockIdx.y;        // p = 0 dispatches first: longest staging loop (LPT)
  const size_t base = (size_t)bh * 2048 * 64;  // elements
  const int b = bh >> 4, h = bh & 15;
  // permuted A-row this lane supplies for fragment f: qrow + 4*(f&1) + 32*(f>>1)
  const int qrow = (q & 3) + 8 * (q >> 2);

  auto stage = [&](int j, int buf) {
    char* Kd = smem + buf * 16384;
    char* Vd = Kd + 8192;
    const int kv0 = j << 6;
    const char* Kg = (const char*)(Kb + base + (size_t)kv0 * 64);
    const char* Vg = (const char*)(Vtb + base) + kv0 * 2;
#pragma unroll
    for (int i = 0; i < 2; ++i) {
      const int chunk = i * 4 + w;                 // [0,8): 8 KB per tile
      const int o = chunk * 1024 + ln * 16;
      const int row = o >> 7;
      const int colb = (o & 127) ^ asb(row);
      gload_lds16(Kg + row * 128 + colb, Kd + chunk * 1024);
      gload_lds16(Vg + (size_t)row * 4096 + colb, Vd + chunk * 1024);
    }
  };

  // causal mask for one q-sub-tile (permuted kv indexing)
  auto mask_diag = [&](f32x4* st, int qw, int kv0) {
#pragma unroll
    for (int f = 0; f < 4; ++f) {
      const int kvb = kv0 + 8 * g + 4 * (f & 1) + 32 * (f >> 1);
#pragma unroll
      for (int r = 0; r < 4; ++r)
        if (kvb + r > qw + q) st[f][r] = -INFINITY;
    }
  };

  // online softmax (base-2; Q pre-scaled log2e/8): st -> P bf16 in pb0/pb1
  auto softmax_pb = [&](f32x4* st, float& m_run, float& l_run, f32x4* yt,
                        uint4& pb0, uint4& pb1) {
    float vmax = -INFINITY;
#pragma unroll
    for (int f = 0; f < 4; ++f) {
      const f32x4 v = st[f];
      vmax = fmaxf(fmaxf(vmax, fmaxf(v[0], v[1])), fmaxf(v[2], v[3]));
    }
    vmax = fmaxf(vmax, __shfl_xor(vmax, 16));
    vmax = fmaxf(vmax, __shfl_xor(vmax, 32));
    const float mo = m_run;
    if (__any(vmax > mo)) {  // exact skip: if no lane grows, corr == 1 exactly
      const float mn = fmaxf(mo, vmax);
      const float corr = exp2_fast(mo - mn);
      m_run = mn;
      l_run *= corr;
#pragma unroll
      for (int mfd = 0; mfd < 4; ++mfd) yt[mfd] *= corr;
    }
    const float mcur = m_run;
    float ls = 0.f;
#pragma unroll
    for (int f = 0; f < 4; ++f) {
#pragma unroll
      for (int r = 0; r < 4; ++r) {
        st[f][r] = exp2_fast(st[f][r] - mcur);
        ls += st[f][r];
      }
    }
    ls += __shfl_xor(ls, 16);
    ls += __shfl_xor(ls, 32);
    l_run += ls;
    pb0.x = cvt_pk_bf16(st[0][0], st[0][1]);
    pb0.y = cvt_pk_bf16(st[0][2], st[0][3]);
    pb0.z = cvt_pk_bf16(st[1][0], st[1][1]);
    pb0.w = cvt_pk_bf16(st[1][2], st[1][3]);
    pb1.x = cvt_pk_bf16(st[2][0], st[2][1]);
    pb1.y = cvt_pk_bf16(st[2][2], st[2][3]);
    pb1.z = cvt_pk_bf16(st[3][0], st[3][1]);
    pb1.w = cvt_pk_bf16(st[3][2], st[3][3]);
  };

  auto epilogue = [&](float l_run, const f32x4* yt, int qw) {
    const float inv = 1.f / l_run;
    const int qr = qw + q;
    unsigned short* yp = Yb + (size_t)(b * 2048 + qr) * 1024 + h * 64;
#pragma unroll
    for (int mfd = 0; mfd < 4; ++mfd) {
      uint2 o2;
      o2.x = cvt_pk_bf16(yt[mfd][0] * inv, yt[mfd][1] * inv);
      o2.y = cvt_pk_bf16(yt[mfd][2] * inv, yt[mfd][3] * inv);
      *(uint2*)(yp + mfd * 16 + g * 4) = o2;
    }
  };

  const int hi = 31 - pair, lo = pair;
  const int qw_hi = hi * 64 + w * 16;
  const int qw_lo = lo * 64 + w * 16;

  bf16x8 qh[2], ql[2];
#pragma unroll
  for (int kf = 0; kf < 2; ++kf) {
    qh[kf] = ld16(Qb + base + (size_t)(qw_hi + q) * 64 + kf * 32 + g * 8);
    ql[kf] = ld16(Qb + base + (size_t)(qw_lo + q) * 64 + kf * 32 + g * 8);
  }
  WAIT_VMCNT(0);  // drain Q loads so the stage-pipeline vmcnt counts stay exact

  float m_hi = -INFINITY, l_hi = 0.f, m_lo = -INFINITY, l_lo = 0.f;
  f32x4 yh[4] = {}, yl[4] = {};

  const int njv = hi + 1;  // 32 - pair staged tiles
  stage(0, 0);
  for (int j = 0; j < njv; ++j) {
    if (j + 1 < njv) {
      stage(j + 1, (j + 1) & 1);
      WAIT_VMCNT(4);
    } else {
      WAIT_VMCNT(0);
    }
    bar();

    const int kv0 = j << 6;
    const char* Ksm = smem + (j & 1) * 16384;
    const char* Vsm = Ksm + 8192;
    const bool dual = (j <= lo);  // block-uniform: lo tile's stream is a prefix

    // ---- shared K fragments (loaded ONCE, consumed by hi and, if dual, lo) ----
    bf16x8 a0[4], a1[4];
#pragma unroll
    for (int f = 0; f < 4; ++f) {
      const int row = qrow + 4 * (f & 1) + 32 * (f >> 1);  // permuted K row
      const int swz = asb(row);
      a0[f] = ld16(Ksm + ((row * 128 + g * 16) ^ swz));
      a1[f] = ld16(Ksm + ((row * 128 + 64 + g * 16) ^ swz));
    }
    // ---- QK^T (hi always, lo if dual) ----
    f32x4 sh[4] = {}, sl[4] = {};
    __builtin_amdgcn_s_setprio(1);
#pragma unroll
    for (int f = 0; f < 4; ++f) {
      sh[f] = mfma16(a0[f], qh[0], sh[f]);
      sh[f] = mfma16(a1[f], qh[1], sh[f]);
    }
    if (dual) {
#pragma unroll
      for (int f = 0; f < 4; ++f) {
        sl[f] = mfma16(a0[f], ql[0], sl[f]);
        sl[f] = mfma16(a1[f], ql[1], sl[f]);
      }
    }
    __builtin_amdgcn_s_setprio(0);
    // ---- masks + softmax ----
    if (kv0 + 63 > qw_hi) mask_diag(sh, qw_hi, kv0);
    uint4 ph0, ph1, pl0, pl1;
    softmax_pb(sh, m_hi, l_hi, yh, ph0, ph1);
    if (dual) {
      if (kv0 + 63 > qw_lo) mask_diag(sl, qw_lo, kv0);
      softmax_pb(sl, m_lo, l_lo, yl, pl0, pl1);
    }
    // ---- shared V fragments + PV ----
    bf16x8 v0[4], v1[4];
#pragma unroll
    for (int mfd = 0; mfd < 4; ++mfd) {
      const int vrow = mfd * 16 + q;
      const int swz = asb(vrow);
      v0[mfd] = ld16(Vsm + ((vrow * 128 + g * 16) ^ swz));
      v1[mfd] = ld16(Vsm + ((vrow * 128 + 64 + g * 16) ^ swz));
    }
    union { uint4 u; bf16x8 bb; } c0, c1;
    __builtin_amdgcn_s_setprio(1);
    c0.u = ph0; c1.u = ph1;
#pragma unroll
    for (int mfd = 0; mfd < 4; ++mfd) {
      yh[mfd] = mfma16(v0[mfd], c0.bb, yh[mfd]);
      yh[mfd] = mfma16(v1[mfd], c1.bb, yh[mfd]);
    }
    if (dual) {
      c0.u = pl0; c1.u = pl1;
#pragma unroll
      for (int mfd = 0; mfd < 4; ++mfd) {
        yl[mfd] = mfma16(v0[mfd], c0.bb, yl[mfd]);
        yl[mfd] = mfma16(v1[mfd], c1.bb, yl[mfd]);
      }
    }
    __builtin_amdgcn_s_setprio(0);
    bar();  // all waves done reading buf before next stage overwrites
  }

  epilogue(l_hi, yh, qw_hi);
  epilogue(l_lo, yl, qw_lo);
}

extern "C" void kernel_launch(void* const* d_in, const int* in_sizes, int n_in,
                              void* d_out, int out_size, void* d_ws, size_t ws_size,
                              hipStream_t stream) {
  const float* x      = (const float*)d_in[0];
  const float* w_qkv  = (const float*)d_in[1];
  const float* b_qkv  = (const float*)d_in[2];
  const float* w_proj = (const float*)d_in[3];
  const float* b_proj = (const float*)d_in[4];
  float* out = (float*)d_out;
  char* ws = (char*)d_ws;

  unsigned short* xb  = (unsigned short*)(ws);                       // 16 MB x bf16
  unsigned short* wqb = (unsigned short*)(ws + (size_t)(16 << 20));  //  6 MB w_qkv bf16
  unsigned short* wpb = (unsigned short*)(ws + (size_t)(22 << 20));  //  2 MB w_proj bf16
  unsigned short* Qb  = (unsigned short*)(ws + (size_t)(24 << 20));  // 16 MB Q (pre-scaled log2e/8)
  unsigned short* Kb  = (unsigned short*)(ws + (size_t)(40 << 20));  // 16 MB K [bh][t][d]
  unsigned short* Vtb = (unsigned short*)(ws + (size_t)(56 << 20));  // 16 MB V^T [bh][d][t]
  unsigned short* Yb  = (unsigned short*)(ws + (size_t)(72 << 20));  // 16 MB attn out bf16

  cvt_all<<<12288, 256, 0, stream>>>(x, w_qkv, w_proj, xb, wqb, wpb);
  gemm_bt<3072, 1><<<dim3(64, 24), 256, 0, stream>>>(xb, wqb, b_qkv, nullptr, Qb, Kb, Vtb);
  attn_fwd<<<dim3(64, 16), 256, 0, stream>>>(Qb, Kb, Vtb, Yb);
  gemm_bt<1024, 0><<<dim3(64, 8), 256, 0, stream>>>(Yb, wpb, b_proj, out, nullptr, nullptr, nullptr);
}

// Round 15
// 183.639 us; speedup vs baseline: 1.0189x; 1.0189x over previous
//
#include <hip/hip_runtime.h>

typedef __bf16 bf16x8 __attribute__((ext_vector_type(8)));
typedef float f32x4 __attribute__((ext_vector_type(4)));

#define DI __device__ __forceinline__

// Pinned counted waitcnt: memory clobber + sched_barrier so global_load_lds
// intrinsics cannot be reordered around it (rule #18).
#define WAIT_VMCNT(N)                                        \
  do {                                                       \
    __builtin_amdgcn_sched_barrier(0);                       \
    asm volatile("s_waitcnt vmcnt(" #N ")" ::: "memory");    \
    __builtin_amdgcn_sched_barrier(0);                       \
  } while (0)

DI unsigned short f2bf(float f) {
  unsigned int u = __float_as_uint(f);
  u += 0x7FFFu + ((u >> 16) & 1u);
  return (unsigned short)(u >> 16);
}

DI unsigned cvt_pk_bf16(float a, float b) {  // lo=bf16(a), hi=bf16(b)
  unsigned r;
  asm("v_cvt_pk_bf16_f32 %0, %1, %2" : "=v"(r) : "v"(a), "v"(b));
  return r;
}

DI float exp2_fast(float x) {  // raw v_exp_f32 (2^x); exp2(-inf)=0
  float r;
  asm("v_exp_f32 %0, %1" : "=v"(r) : "v"(x));
  return r;
}

DI void fence() { asm volatile("" ::: "memory"); }
DI void bar() { fence(); __builtin_amdgcn_s_barrier(); fence(); }

DI bf16x8 ld16(const void* p) {
  union { uint4 u; bf16x8 b; } c;
  c.u = *reinterpret_cast<const uint4*>(p);
  return c.b;
}

DI f32x4 mfma16(bf16x8 a, bf16x8 b, f32x4 c) {
  return __builtin_amdgcn_mfma_f32_16x16x32_bf16(a, b, c, 0, 0, 0);
}

DI void gload_lds16(const void* g, void* l) {
  __builtin_amdgcn_global_load_lds(
      (const __attribute__((address_space(1))) unsigned int*)g,
      (__attribute__((address_space(3))) unsigned int*)l, 16, 0, 0);
}

// ---------------- fused fp32 -> bf16 convert (x, w_qkv, w_proj) ----------------
__global__ void cvt_all(const float* __restrict__ x, const float* __restrict__ wq,
                        const float* __restrict__ wp,
                        unsigned short* __restrict__ xb, unsigned short* __restrict__ wqb,
                        unsigned short* __restrict__ wpb) {
  int i = blockIdx.x * blockDim.x + threadIdx.x;  // float4 index
  const float* s;
  unsigned short* d;
  int off;
  if (i < 2097152) { s = x; d = xb; off = i; }
  else if (i < 2097152 + 786432) { s = wq; d = wqb; off = i - 2097152; }
  else { s = wp; d = wpb; off = i - (2097152 + 786432); }
  float4 v = reinterpret_cast<const float4*>(s)[off];
  uint2 o;
  o.x = cvt_pk_bf16(v.x, v.y);
  o.y = cvt_pk_bf16(v.z, v.w);
  reinterpret_cast<uint2*>(d)[off] = o;
}

// ---------------- GEMM: C[M,N] = A[M,K] * W[N,K]^T + bias ----------------
// PROVEN round-1 structure: 128x128 tile, BK=64, 4 waves (2x2), single-buffered
// LDS (A 16K | B 16K), full drain + barrier per K-step. XOR bank-swizzle on the
// pre-swizzled global source + again on ds_read (involution).
// NEW (T1): bijective XCD-chunked block swizzle (grid sizes are %8==0) --
// consecutive same-XCD slots share W-panels -> per-XCD L2 locality.
// MODE 0: out = fp32 row-major [M][N] (+bias)
// MODE 1: qkv scatter -> Q (scaled log2e/8), K head-major; V transposed [bh][d][t]
//         (V^T stores packed as uint2: in-lane r's are 4 consecutive t)
template <int N, int MODE>
__global__ __launch_bounds__(256)
void gemm_bt(const unsigned short* __restrict__ A,
             const unsigned short* __restrict__ W,
             const float* __restrict__ bias,
             float* __restrict__ out,
             unsigned short* __restrict__ qo,
             unsigned short* __restrict__ ko,
             unsigned short* __restrict__ vo) {
  constexpr int K = 1024;
  __shared__ __align__(16) char smem[32768];  // A tile 16K | B tile 16K
  char* Asm = smem;
  char* Bsm = smem + 16384;
  const int tid = threadIdx.x;
  const int ln = tid & 63;
  const int w  = tid >> 6;
  const int wm = w >> 1, wn = w & 1;
  const int g = ln >> 4, q = ln & 15;
  // XCD-chunked swizzle: linear id (x fastest) -> xcd gets contiguous chunk.
  const int nwg = gridDim.x * gridDim.y;          // %8 == 0 for both launches
  const int lid = blockIdx.y * gridDim.x + blockIdx.x;
  const int sw  = (lid & 7) * (nwg >> 3) + (lid >> 3);
  const int m0 = (sw % gridDim.x) * 128;
  const int n0 = (sw / gridDim.x) * 128;

  f32x4 acc[4][4] = {};

  for (int kt = 0; kt < K / 64; ++kt) {
    if (kt) bar();  // previous compute's LDS reads done before overwrite
#pragma unroll
    for (int i = 0; i < 4; ++i) {
      const int chunk = i * 4 + w;                 // [0,16): full 16 KB tile
      const int o = chunk * 1024 + ln * 16;
      const int row = o >> 7;
      const int colb = (o & 127) ^ ((row & 7) << 4);
      gload_lds16((const char*)A + ((size_t)(m0 + row) * K + kt * 64) * 2 + colb,
                  Asm + chunk * 1024);
      gload_lds16((const char*)W + ((size_t)(n0 + row) * K + kt * 64) * 2 + colb,
                  Bsm + chunk * 1024);
    }
    WAIT_VMCNT(0);
    bar();
#pragma unroll
    for (int ks = 0; ks < 2; ++ks) {
      bf16x8 av[4], bv[4];
#pragma unroll
      for (int mf = 0; mf < 4; ++mf) {
        const int row = wm * 64 + mf * 16 + q;
        av[mf] = ld16(Asm + ((row * 128 + ks * 64 + g * 16) ^ ((row & 7) << 4)));
      }
#pragma unroll
      for (int nf = 0; nf < 4; ++nf) {
        const int row = wn * 64 + nf * 16 + q;
        bv[nf] = ld16(Bsm + ((row * 128 + ks * 64 + g * 16) ^ ((row & 7) << 4)));
      }
#pragma unroll
      for (int mf = 0; mf < 4; ++mf)
#pragma unroll
        for (int nf = 0; nf < 4; ++nf)
          acc[mf][nf] = mfma16(av[mf], bv[nf], acc[mf][nf]);
    }
  }

#pragma unroll
  for (int nf = 0; nf < 4; ++nf) {
    const int col = n0 + wn * 64 + nf * 16 + q;
    const float bv = bias[col];
#pragma unroll
    for (int mf = 0; mf < 4; ++mf) {
      const int rbase = m0 + wm * 64 + mf * 16 + g * 4;
      if constexpr (MODE == 0) {
#pragma unroll
        for (int r = 0; r < 4; ++r)
          out[(size_t)(rbase + r) * N + col] = acc[mf][nf][r] + bv;
      } else {
        const int b = rbase >> 11, t0 = rbase & 2047;  // 4 consecutive t, same b
        if (col < 1024) {
          const int h = col >> 6, d = col & 63;
          unsigned short* qp = qo + ((((size_t)b * 16 + h) << 11) + t0) * 64 + d;
#pragma unroll
          for (int r = 0; r < 4; ++r)
            qp[r * 64] = f2bf((acc[mf][nf][r] + bv) * 0.18033688011112042f);
        } else if (col < 2048) {
          const int c = col - 1024;
          const int h = c >> 6, d = c & 63;
          unsigned short* kp = ko + ((((size_t)b * 16 + h) << 11) + t0) * 64 + d;
#pragma unroll
          for (int r = 0; r < 4; ++r)
            kp[r * 64] = f2bf(acc[mf][nf][r] + bv);
        } else {
          const int c = col - 2048;
          const int h = c >> 6, d = c & 63;
          uint2 pk;
          pk.x = cvt_pk_bf16(acc[mf][nf][0] + bv, acc[mf][nf][1] + bv);
          pk.y = cvt_pk_bf16(acc[mf][nf][2] + bv, acc[mf][nf][3] + bv);
          *(uint2*)(vo + ((((size_t)b * 16 + h) << 6) + d) * 2048 + t0) = pk;
        }
      }
    }
  }
}

// attention swizzle: slot bits 0-1 from row bits 0-1, slot bit 2 from row BIT 3.
// Conflict-free for both the permuted K-read and the V-read (r12, measured 0).
DI int asb(int row) { return ((row & 3) | (((row >> 3) & 1) << 2)) << 4; }

// ---------------- flash attention (causal), MERGED-PAIR, ZERO-EXCHANGE PV ----------------
// r13 EXACT (best measured: 74 us): one merged kv-loop of 32-p staged tiles;
// hi consumes all, lo consumes j<=p (block-uniform branch); K/V dbuf + counted
// vmcnt(4); permuted-A-row QK^T (P stays in-lane); in-register PV B-operand;
// asb() conflict-free swizzle. Sequential tile_steps keep peak-live <= 64 VGPR —
// the r14 fragment-sharing variant spilled to scratch (WRITE_SIZE 16->37 MB).
__global__ __launch_bounds__(256, 4)
void attn_fwd(const unsigned short* __restrict__ Qb,
              const unsigned short* __restrict__ Kb,
              const unsigned short* __restrict__ Vtb,
              unsigned short* __restrict__ Yb) {
  __shared__ __align__(16) char smem[32768];
  // buf0: K [0,8K) V [8K,16K); buf1: K [16K,24K) V [24K,32K)
  const int tid = threadIdx.x;
  const int ln = tid & 63;
  const int w = tid >> 6;
  const int g = ln >> 4, q = ln & 15;
  const int bh = blockIdx.x;
  const int pair = blockIdx.y;        // p = 0 dispatches first: longest staging loop (LPT)
  const size_t base = (size_t)bh * 2048 * 64;  // elements
  const int b = bh >> 4, h = bh & 15;
  // permuted A-row this lane supplies for fragment f: qrow + 4*(f&1) + 32*(f>>1)
  const int qrow = (q & 3) + 8 * (q >> 2);

  auto stage = [&](int j, int buf) {
    char* Kd = smem + buf * 16384;
    char* Vd = Kd + 8192;
    const int kv0 = j << 6;
    const char* Kg = (const char*)(Kb + base + (size_t)kv0 * 64);
    const char* Vg = (const char*)(Vtb + base) + kv0 * 2;
#pragma unroll
    for (int i = 0; i < 2; ++i) {
      const int chunk = i * 4 + w;                 // [0,8): 8 KB per tile
      const int o = chunk * 1024 + ln * 16;
      const int row = o >> 7;
      const int colb = (o & 127) ^ asb(row);
      gload_lds16(Kg + row * 128 + colb, Kd + chunk * 1024);
      gload_lds16(Vg + (size_t)row * 4096 + colb, Vd + chunk * 1024);
    }
  };

  // one kv-tile of online-softmax attention for one q-sub-tile (16 rows/wave)
  auto tile_step = [&](const bf16x8* qf, float& m_run, float& l_run, f32x4* yt,
                       int qw, int kv0, const char* Ksm, const char* Vsm) {
    // ---- QK^T with permuted A-rows: st[f][r] = S[kv0 + 8g + 4(f&1) + 32(f>>1) + r][qw+q]
    f32x4 st[4] = {};
    __builtin_amdgcn_s_setprio(1);
#pragma unroll
    for (int f = 0; f < 4; ++f) {
      const int row = qrow + 4 * (f & 1) + 32 * (f >> 1);  // permuted K row
      const int swz = asb(row);
      const bf16x8 a0 = ld16(Ksm + ((row * 128 + g * 16) ^ swz));
      const bf16x8 a1 = ld16(Ksm + ((row * 128 + 64 + g * 16) ^ swz));
      st[f] = mfma16(a0, qf[0], st[f]);
      st[f] = mfma16(a1, qf[1], st[f]);
    }
    __builtin_amdgcn_s_setprio(0);
    if (kv0 + 63 > qw) {  // diagonal tile: causal mask (permuted kv indexing)
#pragma unroll
      for (int f = 0; f < 4; ++f) {
        const int kvb = kv0 + 8 * g + 4 * (f & 1) + 32 * (f >> 1);
#pragma unroll
        for (int r = 0; r < 4; ++r)
          if (kvb + r > qw + q) st[f][r] = -INFINITY;
      }
    }
    // ---- online softmax (base-2 domain; Q pre-scaled log2e/8), all in-lane ----
    {
      float vmax = -INFINITY;
#pragma unroll
      for (int f = 0; f < 4; ++f) {
        const f32x4 v = st[f];
        vmax = fmaxf(fmaxf(vmax, fmaxf(v[0], v[1])), fmaxf(v[2], v[3]));
      }
      vmax = fmaxf(vmax, __shfl_xor(vmax, 16));
      vmax = fmaxf(vmax, __shfl_xor(vmax, 32));
      const float mo = m_run;
      if (__any(vmax > mo)) {  // exact skip: if no lane grows, corr == 1 exactly
        const float mn = fmaxf(mo, vmax);
        const float corr = exp2_fast(mo - mn);
        m_run = mn;
        l_run *= corr;
#pragma unroll
        for (int mfd = 0; mfd < 4; ++mfd) yt[mfd] *= corr;
      }
      const float mcur = m_run;
      float ls = 0.f;
#pragma unroll
      for (int f = 0; f < 4; ++f) {
#pragma unroll
        for (int r = 0; r < 4; ++r) {
          st[f][r] = exp2_fast(st[f][r] - mcur);
          ls += st[f][r];
        }
      }
      ls += __shfl_xor(ls, 16);
      ls += __shfl_xor(ls, 32);
      l_run += ls;
    }
    // ---- PV B-operand built IN-REGISTER (zero exchange) ----
    union { uint4 u; bf16x8 bb; } pb0, pb1;
    pb0.u.x = cvt_pk_bf16(st[0][0], st[0][1]);
    pb0.u.y = cvt_pk_bf16(st[0][2], st[0][3]);
    pb0.u.z = cvt_pk_bf16(st[1][0], st[1][1]);
    pb0.u.w = cvt_pk_bf16(st[1][2], st[1][3]);
    pb1.u.x = cvt_pk_bf16(st[2][0], st[2][1]);
    pb1.u.y = cvt_pk_bf16(st[2][2], st[2][3]);
    pb1.u.z = cvt_pk_bf16(st[3][0], st[3][1]);
    pb1.u.w = cvt_pk_bf16(st[3][2], st[3][3]);
    // PV: Y^T[d][q] += Vt * P^T
    __builtin_amdgcn_s_setprio(1);
#pragma unroll
    for (int mfd = 0; mfd < 4; ++mfd) {
      const int vrow = mfd * 16 + q;
      const int swz = asb(vrow);
      const bf16x8 v0 = ld16(Vsm + ((vrow * 128 + g * 16) ^ swz));
      const bf16x8 v1 = ld16(Vsm + ((vrow * 128 + 64 + g * 16) ^ swz));
      yt[mfd] = mfma16(v0, pb0.bb, yt[mfd]);
      yt[mfd] = mfma16(v1, pb1.bb, yt[mfd]);
    }
    __builtin_amdgcn_s_setprio(0);
  };

  auto epilogue = [&](float l_run, const f32x4* yt, int qw) {
    const float inv = 1.f / l_run;
    const int qr = qw + q;
    unsigned short* yp = Yb + (size_t)(b * 2048 + qr) * 1024 + h * 64;
#pragma unroll
    for (int mfd = 0; mfd < 4; ++mfd) {
      uint2 o2;
      o2.x = cvt_pk_bf16(yt[mfd][0] * inv, yt[mfd][1] * inv);
      o2.y = cvt_pk_bf16(yt[mfd][2] * inv, yt[mfd][3] * inv);
      *(uint2*)(yp + mfd * 16 + g * 4) = o2;
    }
  };

  const int hi = 31 - pair, lo = pair;
  const int qw_hi = hi * 64 + w * 16;
  const int qw_lo = lo * 64 + w * 16;

  bf16x8 qh[2], ql[2];
#pragma unroll
  for (int kf = 0; kf < 2; ++kf) {
    qh[kf] = ld16(Qb + base + (size_t)(qw_hi + q) * 64 + kf * 32 + g * 8);
    ql[kf] = ld16(Qb + base + (size_t)(qw_lo + q) * 64 + kf * 32 + g * 8);
  }
  WAIT_VMCNT(0);  // drain Q loads so the stage-pipeline vmcnt counts stay exact

  float m_hi = -INFINITY, l_hi = 0.f, m_lo = -INFINITY, l_lo = 0.f;
  f32x4 yh[4] = {}, yl[4] = {};

  const int njv = hi + 1;  // 32 - pair staged tiles
  stage(0, 0);
  for (int j = 0; j < njv; ++j) {
    if (j + 1 < njv) {
      stage(j + 1, (j + 1) & 1);
      WAIT_VMCNT(4);
    } else {
      WAIT_VMCNT(0);
    }
    bar();

    const int kv0 = j << 6;
    const char* Ksm = smem + (j & 1) * 16384;
    const char* Vsm = Ksm + 8192;
    tile_step(qh, m_hi, l_hi, yh, qw_hi, kv0, Ksm, Vsm);
    if (j <= lo)  // block-uniform branch: lo tile's stream is a prefix
      tile_step(ql, m_lo, l_lo, yl, qw_lo, kv0, Ksm, Vsm);
    bar();  // all waves done reading buf before next stage overwrites
  }

  epilogue(l_hi, yh, qw_hi);
  epilogue(l_lo, yl, qw_lo);
}

extern "C" void kernel_launch(void* const* d_in, const int* in_sizes, int n_in,
                              void* d_out, int out_size, void* d_ws, size_t ws_size,
                              hipStream_t stream) {
  const float* x      = (const float*)d_in[0];
  const float* w_qkv  = (const float*)d_in[1];
  const float* b_qkv  = (const float*)d_in[2];
  const float* w_proj = (const float*)d_in[3];
  const float* b_proj = (const float*)d_in[4];
  float* out = (float*)d_out;
  char* ws = (char*)d_ws;

  unsigned short* xb  = (unsigned short*)(ws);                       // 16 MB x bf16
  unsigned short* wqb = (unsigned short*)(ws + (size_t)(16 << 20));  //  6 MB w_qkv bf16
  unsigned short* wpb = (unsigned short*)(ws + (size_t)(22 << 20));  //  2 MB w_proj bf16
  unsigned short* Qb  = (unsigned short*)(ws + (size_t)(24 << 20));  // 16 MB Q (pre-scaled log2e/8)
  unsigned short* Kb  = (unsigned short*)(ws + (size_t)(40 << 20));  // 16 MB K [bh][t][d]
  unsigned short* Vtb = (unsigned short*)(ws + (size_t)(56 << 20));  // 16 MB V^T [bh][d][t]
  unsigned short* Yb  = (unsigned short*)(ws + (size_t)(72 << 20));  // 16 MB attn out bf16

  cvt_all<<<12288, 256, 0, stream>>>(x, w_qkv, w_proj, xb, wqb, wpb);
  gemm_bt<3072, 1><<<dim3(64, 24), 256, 0, stream>>>(xb, wqb, b_qkv, nullptr, Qb, Kb, Vtb);
  attn_fwd<<<dim3(64, 16), 256, 0, stream>>>(Qb, Kb, Vtb, Yb);
  gemm_bt<1024, 0><<<dim3(64, 8), 256, 0, stream>>>(Yb, wpb, b_proj, out, nullptr, nullptr, nullptr);
}

// Round 16
// 160.724 us; speedup vs baseline: 1.1642x; 1.1426x over previous
//
#include <hip/hip_runtime.h>

typedef __bf16 bf16x8 __attribute__((ext_vector_type(8)));
typedef float f32x4 __attribute__((ext_vector_type(4)));

#define DI __device__ __forceinline__

// Pinned counted waitcnt: memory clobber + sched_barrier so global_load_lds
// intrinsics cannot be reordered around it (rule #18).
#define WAIT_VMCNT(N)                                        \
  do {                                                       \
    __builtin_amdgcn_sched_barrier(0);                       \
    asm volatile("s_waitcnt vmcnt(" #N ")" ::: "memory");    \
    __builtin_amdgcn_sched_barrier(0);                       \
  } while (0)

DI unsigned short f2bf(float f) {
  unsigned int u = __float_as_uint(f);
  u += 0x7FFFu + ((u >> 16) & 1u);
  return (unsigned short)(u >> 16);
}

DI unsigned cvt_pk_bf16(float a, float b) {  // lo=bf16(a), hi=bf16(b)
  unsigned r;
  asm("v_cvt_pk_bf16_f32 %0, %1, %2" : "=v"(r) : "v"(a), "v"(b));
  return r;
}

DI float exp2_fast(float x) {  // raw v_exp_f32 (2^x); exp2(-inf)=0
  float r;
  asm("v_exp_f32 %0, %1" : "=v"(r) : "v"(x));
  return r;
}

DI void fence() { asm volatile("" ::: "memory"); }
DI void bar() { fence(); __builtin_amdgcn_s_barrier(); fence(); }

DI bf16x8 ld16(const void* p) {
  union { uint4 u; bf16x8 b; } c;
  c.u = *reinterpret_cast<const uint4*>(p);
  return c.b;
}

DI f32x4 mfma16(bf16x8 a, bf16x8 b, f32x4 c) {
  return __builtin_amdgcn_mfma_f32_16x16x32_bf16(a, b, c, 0, 0, 0);
}

DI void gload_lds16(const void* g, void* l) {
  __builtin_amdgcn_global_load_lds(
      (const __attribute__((address_space(1))) unsigned int*)g,
      (__attribute__((address_space(3))) unsigned int*)l, 16, 0, 0);
}

// ---------------- fused fp32 -> bf16 convert (x, w_qkv, w_proj) ----------------
__global__ void cvt_all(const float* __restrict__ x, const float* __restrict__ wq,
                        const float* __restrict__ wp,
                        unsigned short* __restrict__ xb, unsigned short* __restrict__ wqb,
                        unsigned short* __restrict__ wpb) {
  int i = blockIdx.x * blockDim.x + threadIdx.x;  // float4 index
  const float* s;
  unsigned short* d;
  int off;
  if (i < 2097152) { s = x; d = xb; off = i; }
  else if (i < 2097152 + 786432) { s = wq; d = wqb; off = i - 2097152; }
  else { s = wp; d = wpb; off = i - (2097152 + 786432); }
  float4 v = reinterpret_cast<const float4*>(s)[off];
  uint2 o;
  o.x = cvt_pk_bf16(v.x, v.y);
  o.y = cvt_pk_bf16(v.z, v.w);
  reinterpret_cast<uint2*>(d)[off] = o;
}

// ---------------- GEMM: C[M,N] = A[M,K] * W[N,K]^T + bias ----------------
// PROVEN round-1 structure: 128x128 tile, BK=64, 4 waves (2x2), single-buffered
// LDS (A 16K | B 16K), full drain + barrier per K-step. XOR bank-swizzle on the
// pre-swizzled global source + again on ds_read (involution). NATURAL block
// mapping (r15's XCD-chunked swizzle destroyed L3 locality: FETCH 186MB, -20us).
// MODE 0: out = fp32 row-major [M][N] (+bias)
// MODE 1: qkv scatter -> Q (scaled log2e/8), K head-major; V transposed [bh][d][t]
//         (V^T stores packed as uint2: in-lane r's are 4 consecutive t)
template <int N, int MODE>
__global__ __launch_bounds__(256)
void gemm_bt(const unsigned short* __restrict__ A,
             const unsigned short* __restrict__ W,
             const float* __restrict__ bias,
             float* __restrict__ out,
             unsigned short* __restrict__ qo,
             unsigned short* __restrict__ ko,
             unsigned short* __restrict__ vo) {
  constexpr int K = 1024;
  __shared__ __align__(16) char smem[32768];  // A tile 16K | B tile 16K
  char* Asm = smem;
  char* Bsm = smem + 16384;
  const int tid = threadIdx.x;
  const int ln = tid & 63;
  const int w  = tid >> 6;
  const int wm = w >> 1, wn = w & 1;
  const int g = ln >> 4, q = ln & 15;
  const int m0 = blockIdx.x * 128;
  const int n0 = blockIdx.y * 128;

  f32x4 acc[4][4] = {};

  for (int kt = 0; kt < K / 64; ++kt) {
    if (kt) bar();  // previous compute's LDS reads done before overwrite
#pragma unroll
    for (int i = 0; i < 4; ++i) {
      const int chunk = i * 4 + w;                 // [0,16): full 16 KB tile
      const int o = chunk * 1024 + ln * 16;
      const int row = o >> 7;
      const int colb = (o & 127) ^ ((row & 7) << 4);
      gload_lds16((const char*)A + ((size_t)(m0 + row) * K + kt * 64) * 2 + colb,
                  Asm + chunk * 1024);
      gload_lds16((const char*)W + ((size_t)(n0 + row) * K + kt * 64) * 2 + colb,
                  Bsm + chunk * 1024);
    }
    WAIT_VMCNT(0);
    bar();
#pragma unroll
    for (int ks = 0; ks < 2; ++ks) {
      bf16x8 av[4], bv[4];
#pragma unroll
      for (int mf = 0; mf < 4; ++mf) {
        const int row = wm * 64 + mf * 16 + q;
        av[mf] = ld16(Asm + ((row * 128 + ks * 64 + g * 16) ^ ((row & 7) << 4)));
      }
#pragma unroll
      for (int nf = 0; nf < 4; ++nf) {
        const int row = wn * 64 + nf * 16 + q;
        bv[nf] = ld16(Bsm + ((row * 128 + ks * 64 + g * 16) ^ ((row & 7) << 4)));
      }
#pragma unroll
      for (int mf = 0; mf < 4; ++mf)
#pragma unroll
        for (int nf = 0; nf < 4; ++nf)
          acc[mf][nf] = mfma16(av[mf], bv[nf], acc[mf][nf]);
    }
  }

#pragma unroll
  for (int nf = 0; nf < 4; ++nf) {
    const int col = n0 + wn * 64 + nf * 16 + q;
    const float bv = bias[col];
#pragma unroll
    for (int mf = 0; mf < 4; ++mf) {
      const int rbase = m0 + wm * 64 + mf * 16 + g * 4;
      if constexpr (MODE == 0) {
#pragma unroll
        for (int r = 0; r < 4; ++r)
          out[(size_t)(rbase + r) * N + col] = acc[mf][nf][r] + bv;
      } else {
        const int b = rbase >> 11, t0 = rbase & 2047;  // 4 consecutive t, same b
        if (col < 1024) {
          const int h = col >> 6, d = col & 63;
          unsigned short* qp = qo + ((((size_t)b * 16 + h) << 11) + t0) * 64 + d;
#pragma unroll
          for (int r = 0; r < 4; ++r)
            qp[r * 64] = f2bf((acc[mf][nf][r] + bv) * 0.18033688011112042f);
        } else if (col < 2048) {
          const int c = col - 1024;
          const int h = c >> 6, d = c & 63;
          unsigned short* kp = ko + ((((size_t)b * 16 + h) << 11) + t0) * 64 + d;
#pragma unroll
          for (int r = 0; r < 4; ++r)
            kp[r * 64] = f2bf(acc[mf][nf][r] + bv);
        } else {
          const int c = col - 2048;
          const int h = c >> 6, d = c & 63;
          uint2 pk;
          pk.x = cvt_pk_bf16(acc[mf][nf][0] + bv, acc[mf][nf][1] + bv);
          pk.y = cvt_pk_bf16(acc[mf][nf][2] + bv, acc[mf][nf][3] + bv);
          *(uint2*)(vo + ((((size_t)b * 16 + h) << 6) + d) * 2048 + t0) = pk;
        }
      }
    }
  }
}

// attention swizzle: slot bits 0-1 from row bits 0-1, slot bit 2 from row BIT 3.
// Conflict-free for both the permuted K-read and the V-read (r12, measured 0).
DI int asb(int row) { return ((row & 3) | (((row >> 3) & 1) << 2)) << 4; }

// ---------------- flash attention (causal), MERGED-PAIR, ZERO-EXCHANGE PV ----------------
// r13 EXACT (best measured: 74 us): one merged kv-loop of 32-p staged tiles;
// hi consumes all, lo consumes j<=p (block-uniform branch); K/V dbuf + counted
// vmcnt(4); permuted-A-row QK^T (P stays in-lane); in-register PV B-operand;
// asb() conflict-free swizzle. Sequential tile_steps keep peak-live <= 64 VGPR —
// the r14 fragment-sharing variant spilled to scratch (WRITE_SIZE 16->37 MB).
__global__ __launch_bounds__(256, 4)
void attn_fwd(const unsigned short* __restrict__ Qb,
              const unsigned short* __restrict__ Kb,
              const unsigned short* __restrict__ Vtb,
              unsigned short* __restrict__ Yb) {
  __shared__ __align__(16) char smem[32768];
  // buf0: K [0,8K) V [8K,16K); buf1: K [16K,24K) V [24K,32K)
  const int tid = threadIdx.x;
  const int ln = tid & 63;
  const int w = tid >> 6;
  const int g = ln >> 4, q = ln & 15;
  const int bh = blockIdx.x;
  const int pair = blockIdx.y;        // p = 0 dispatches first: longest staging loop (LPT)
  const size_t base = (size_t)bh * 2048 * 64;  // elements
  const int b = bh >> 4, h = bh & 15;
  // permuted A-row this lane supplies for fragment f: qrow + 4*(f&1) + 32*(f>>1)
  const int qrow = (q & 3) + 8 * (q >> 2);

  auto stage = [&](int j, int buf) {
    char* Kd = smem + buf * 16384;
    char* Vd = Kd + 8192;
    const int kv0 = j << 6;
    const char* Kg = (const char*)(Kb + base + (size_t)kv0 * 64);
    const char* Vg = (const char*)(Vtb + base) + kv0 * 2;
#pragma unroll
    for (int i = 0; i < 2; ++i) {
      const int chunk = i * 4 + w;                 // [0,8): 8 KB per tile
      const int o = chunk * 1024 + ln * 16;
      const int row = o >> 7;
      const int colb = (o & 127) ^ asb(row);
      gload_lds16(Kg + row * 128 + colb, Kd + chunk * 1024);
      gload_lds16(Vg + (size_t)row * 4096 + colb, Vd + chunk * 1024);
    }
  };

  // one kv-tile of online-softmax attention for one q-sub-tile (16 rows/wave)
  auto tile_step = [&](const bf16x8* qf, float& m_run, float& l_run, f32x4* yt,
                       int qw, int kv0, const char* Ksm, const char* Vsm) {
    // ---- QK^T with permuted A-rows: st[f][r] = S[kv0 + 8g + 4(f&1) + 32(f>>1) + r][qw+q]
    f32x4 st[4] = {};
    __builtin_amdgcn_s_setprio(1);
#pragma unroll
    for (int f = 0; f < 4; ++f) {
      const int row = qrow + 4 * (f & 1) + 32 * (f >> 1);  // permuted K row
      const int swz = asb(row);
      const bf16x8 a0 = ld16(Ksm + ((row * 128 + g * 16) ^ swz));
      const bf16x8 a1 = ld16(Ksm + ((row * 128 + 64 + g * 16) ^ swz));
      st[f] = mfma16(a0, qf[0], st[f]);
      st[f] = mfma16(a1, qf[1], st[f]);
    }
    __builtin_amdgcn_s_setprio(0);
    if (kv0 + 63 > qw) {  // diagonal tile: causal mask (permuted kv indexing)
#pragma unroll
      for (int f = 0; f < 4; ++f) {
        const int kvb = kv0 + 8 * g + 4 * (f & 1) + 32 * (f >> 1);
#pragma unroll
        for (int r = 0; r < 4; ++r)
          if (kvb + r > qw + q) st[f][r] = -INFINITY;
      }
    }
    // ---- online softmax (base-2 domain; Q pre-scaled log2e/8), all in-lane ----
    {
      float vmax = -INFINITY;
#pragma unroll
      for (int f = 0; f < 4; ++f) {
        const f32x4 v = st[f];
        vmax = fmaxf(fmaxf(vmax, fmaxf(v[0], v[1])), fmaxf(v[2], v[3]));
      }
      vmax = fmaxf(vmax, __shfl_xor(vmax, 16));
      vmax = fmaxf(vmax, __shfl_xor(vmax, 32));
      const float mo = m_run;
      if (__any(vmax > mo)) {  // exact skip: if no lane grows, corr == 1 exactly
        const float mn = fmaxf(mo, vmax);
        const float corr = exp2_fast(mo - mn);
        m_run = mn;
        l_run *= corr;
#pragma unroll
        for (int mfd = 0; mfd < 4; ++mfd) yt[mfd] *= corr;
      }
      const float mcur = m_run;
      float ls = 0.f;
#pragma unroll
      for (int f = 0; f < 4; ++f) {
#pragma unroll
        for (int r = 0; r < 4; ++r) {
          st[f][r] = exp2_fast(st[f][r] - mcur);
          ls += st[f][r];
        }
      }
      ls += __shfl_xor(ls, 16);
      ls += __shfl_xor(ls, 32);
      l_run += ls;
    }
    // ---- PV B-operand built IN-REGISTER (zero exchange) ----
    union { uint4 u; bf16x8 bb; } pb0, pb1;
    pb0.u.x = cvt_pk_bf16(st[0][0], st[0][1]);
    pb0.u.y = cvt_pk_bf16(st[0][2], st[0][3]);
    pb0.u.z = cvt_pk_bf16(st[1][0], st[1][1]);
    pb0.u.w = cvt_pk_bf16(st[1][2], st[1][3]);
    pb1.u.x = cvt_pk_bf16(st[2][0], st[2][1]);
    pb1.u.y = cvt_pk_bf16(st[2][2], st[2][3]);
    pb1.u.z = cvt_pk_bf16(st[3][0], st[3][1]);
    pb1.u.w = cvt_pk_bf16(st[3][2], st[3][3]);
    // PV: Y^T[d][q] += Vt * P^T
    __builtin_amdgcn_s_setprio(1);
#pragma unroll
    for (int mfd = 0; mfd < 4; ++mfd) {
      const int vrow = mfd * 16 + q;
      const int swz = asb(vrow);
      const bf16x8 v0 = ld16(Vsm + ((vrow * 128 + g * 16) ^ swz));
      const bf16x8 v1 = ld16(Vsm + ((vrow * 128 + 64 + g * 16) ^ swz));
      yt[mfd] = mfma16(v0, pb0.bb, yt[mfd]);
      yt[mfd] = mfma16(v1, pb1.bb, yt[mfd]);
    }
    __builtin_amdgcn_s_setprio(0);
  };

  auto epilogue = [&](float l_run, const f32x4* yt, int qw) {
    const float inv = 1.f / l_run;
    const int qr = qw + q;
    unsigned short* yp = Yb + (size_t)(b * 2048 + qr) * 1024 + h * 64;
#pragma unroll
    for (int mfd = 0; mfd < 4; ++mfd) {
      uint2 o2;
      o2.x = cvt_pk_bf16(yt[mfd][0] * inv, yt[mfd][1] * inv);
      o2.y = cvt_pk_bf16(yt[mfd][2] * inv, yt[mfd][3] * inv);
      *(uint2*)(yp + mfd * 16 + g * 4) = o2;
    }
  };

  const int hi = 31 - pair, lo = pair;
  const int qw_hi = hi * 64 + w * 16;
  const int qw_lo = lo * 64 + w * 16;

  bf16x8 qh[2], ql[2];
#pragma unroll
  for (int kf = 0; kf < 2; ++kf) {
    qh[kf] = ld16(Qb + base + (size_t)(qw_hi + q) * 64 + kf * 32 + g * 8);
    ql[kf] = ld16(Qb + base + (size_t)(qw_lo + q) * 64 + kf * 32 + g * 8);
  }
  WAIT_VMCNT(0);  // drain Q loads so the stage-pipeline vmcnt counts stay exact

  float m_hi = -INFINITY, l_hi = 0.f, m_lo = -INFINITY, l_lo = 0.f;
  f32x4 yh[4] = {}, yl[4] = {};

  const int njv = hi + 1;  // 32 - pair staged tiles
  stage(0, 0);
  for (int j = 0; j < njv; ++j) {
    if (j + 1 < njv) {
      stage(j + 1, (j + 1) & 1);
      WAIT_VMCNT(4);
    } else {
      WAIT_VMCNT(0);
    }
    bar();

    const int kv0 = j << 6;
    const char* Ksm = smem + (j & 1) * 16384;
    const char* Vsm = Ksm + 8192;
    tile_step(qh, m_hi, l_hi, yh, qw_hi, kv0, Ksm, Vsm);
    if (j <= lo)  // block-uniform branch: lo tile's stream is a prefix
      tile_step(ql, m_lo, l_lo, yl, qw_lo, kv0, Ksm, Vsm);
    bar();  // all waves done reading buf before next stage overwrites
  }

  epilogue(l_hi, yh, qw_hi);
  epilogue(l_lo, yl, qw_lo);
}

extern "C" void kernel_launch(void* const* d_in, const int* in_sizes, int n_in,
                              void* d_out, int out_size, void* d_ws, size_t ws_size,
                              hipStream_t stream) {
  const float* x      = (const float*)d_in[0];
  const float* w_qkv  = (const float*)d_in[1];
  const float* b_qkv  = (const float*)d_in[2];
  const float* w_proj = (const float*)d_in[3];
  const float* b_proj = (const float*)d_in[4];
  float* out = (float*)d_out;
  char* ws = (char*)d_ws;

  unsigned short* xb  = (unsigned short*)(ws);                       // 16 MB x bf16
  unsigned short* wqb = (unsigned short*)(ws + (size_t)(16 << 20));  //  6 MB w_qkv bf16
  unsigned short* wpb = (unsigned short*)(ws + (size_t)(22 << 20));  //  2 MB w_proj bf16
  unsigned short* Qb  = (unsigned short*)(ws + (size_t)(24 << 20));  // 16 MB Q (pre-scaled log2e/8)
  unsigned short* Kb  = (unsigned short*)(ws + (size_t)(40 << 20));  // 16 MB K [bh][t][d]
  unsigned short* Vtb = (unsigned short*)(ws + (size_t)(56 << 20));  // 16 MB V^T [bh][d][t]
  unsigned short* Yb  = (unsigned short*)(ws + (size_t)(72 << 20));  // 16 MB attn out bf16

  cvt_all<<<12288, 256, 0, stream>>>(x, w_qkv, w_proj, xb, wqb, wpb);
  gemm_bt<3072, 1><<<dim3(64, 24), 256, 0, stream>>>(xb, wqb, b_qkv, nullptr, Qb, Kb, Vtb);
  attn_fwd<<<dim3(64, 16), 256, 0, stream>>>(Qb, Kb, Vtb, Yb);
  gemm_bt<1024, 0><<<dim3(64, 8), 256, 0, stream>>>(Yb, wpb, b_proj, out, nullptr, nullptr, nullptr);
}